// Round 2
// baseline (196.496 us; speedup 1.0000x reference)
//
#include <hip/hip_runtime.h>
#include <hip/hip_bf16.h>
#include <stdint.h>

#define BB 2
#define CC 256
#define HH 96
#define WW 320
#define NPIX 16384
#define NLAY 5
#define KDIM 1280   // CC*NLAY
#define NDIM 32768  // BB*NPIX
#define NKT (KDIM / 32)   // 40 K-tiles

typedef float f32x4 __attribute__((ext_vector_type(4)));
typedef float f32x2 __attribute__((ext_vector_type(2)));
typedef __bf16 bf16x8 __attribute__((ext_vector_type(8)));
typedef __bf16 bf16x4 __attribute__((ext_vector_type(4)));

// ---------- K1 (+K3+K5 fused as extra blocks): ----------
// blocks [0,3072): cumsum along W + transpose (B,C,H,W) -> (B,H,W,C).
// blocks [3072,3552): box geometry + Wc repack (1920 old 256-thread blocks
// repacked 4-per-1024-block). Branch is block-uniform -> k1's __syncthreads
// is only reached by k1 blocks (safe).
__global__ __launch_bounds__(1024) void k1f(const float* __restrict__ feat,
                                            float* __restrict__ integ,
                                            const float* __restrict__ gridp,
                                            const float* __restrict__ calib,
                                            const float* __restrict__ Wc,
                                            float4* __restrict__ coords,
                                            float* __restrict__ scales,
                                            __bf16* __restrict__ Wbf) {
  const int bid = blockIdx.x;
  if (bid >= BB * HH * 16) {
    // ---- K3/K5 part ----
    const int vbid = (bid - BB * HH * 16) * 4 + (threadIdx.x >> 8);
    const int vt = threadIdx.x & 255;
    if (vbid >= 640) {                  // K5: repack Wc (co, c*5+n) -> bf16 (co, n*256+c)
      int o = (vbid - 640) * 256 + vt;
      int co = o / KDIM;
      int kk = o % KDIM;
      int n = kk >> 8;
      int c = kk & 255;
      Wbf[o] = (__bf16)Wc[co * KDIM + c * NLAY + n];
      return;
    }
    // K3: one thread per box. Keep SEPARATE from k4 — fusing into k4 makes all
    // 64 lanes redundantly compute 16 fp32 divides (R3: k4 57->173us).
    int box = vbid * 256 + vt;          // ((b*5+n)<<14) | pix
    int pix = box & (NPIX - 1);
    int bn = box >> 14;
    int n = bn % NLAY;
    int b = bn / NLAY;
    const float* cb = calib + b * 12;
    float c00 = cb[0], c01 = cb[1], c02 = cb[2], c03 = cb[3];
    float c10 = cb[4], c11 = cb[5], c12 = cb[6], c13 = cb[7];
    float c20 = cb[8], c21 = cb[9], c22 = cb[10], c23 = cb[11];
    float gx = gridp[pix * 3 + 0], gy = gridp[pix * 3 + 1], gz = gridp[pix * 3 + 2];
    float zoff = 32.0f * (float)n;
    const float ox[8] = {-12.5f, 12.5f, 12.5f, -12.5f, -12.5f, 12.5f, 12.5f, -12.5f};
    const float oy[8] = {-12.5f, -12.5f, 12.5f, 12.5f, -12.5f, -12.5f, 12.5f, 12.5f};
    float xmn = 1e30f, ymn = 1e30f, xmx = -1e30f, ymx = -1e30f;
#pragma unroll
    for (int k = 0; k < 8; ++k) {
      float X = gx + ox[k];
      float Y = gy + oy[k];
      float Z = gz + zoff + ((k >= 4) ? 32.0f : 0.0f);
      float px = c00 * X + c01 * Y + c02 * Z + c03;
      float py = c10 * X + c11 * Y + c12 * Z + c13;
      float pz = c20 * X + c21 * Y + c22 * Z + c23;
      float d = fmaxf(pz, 1e-6f);
      float nx = fminf(fmaxf(2.0f * (px / d) / 320.0f - 1.0f, -1.0f), 0.95f);
      float ny = fminf(fmaxf(2.0f * (py / d) / 96.0f - 1.0f, -1.0f), 0.95f);
      xmn = fminf(xmn, nx); xmx = fmaxf(xmx, nx);
      ymn = fminf(ymn, ny); ymx = fmaxf(ymx, ny);
    }
    float dx = xmx - xmn, dy = ymx - ymn;
    float area = (dx * dy) * 30720.0f + 1e-6f;
    bool vis = (area > 1e-6f) && (area < 9216.0f);
    float X0 = ((xmn + 1.0f) * 320.0f - 1.0f) * 0.5f;
    float Y0 = ((ymn + 1.0f) * 96.0f - 1.0f) * 0.5f;
    float X1 = ((xmx + 1.0f) * 320.0f - 1.0f) * 0.5f;
    float Y1 = ((ymx + 1.0f) * 96.0f - 1.0f) * 0.5f;
    coords[box] = make_float4(X0, Y0, X1, Y1);
    scales[box] = vis ? 1.0f / area : 0.0f;
    return;
  }
  // ---- K1 part: wave-parallel W-scan, one wave per (b,h,c) row ----
  // R1 post-mortem: interleaving the 5 chunk scans (chain 30->7 dep shfls)
  // changed NOTHING (42.7us) -> not chain-latency-bound. Revised theory:
  // DS/crossbar-pipe THROUGHPUT bound: 30 shfl + 10 LDS ops per wave x 32
  // resident waves serializes on the one LDS pipe (~22us of the 42).
  // R2: per-lane RUN scan. Lane owns w in [lane*5, lane*5+5): 5 contiguous
  // loads (wave still covers the same 1280B row -> same HBM traffic, L1
  // absorbs per-instr stride), 4 serial VALU adds, then ONE 6-step shfl
  // scan over lane totals. DS ops/wave: 40 -> 16.
  __shared__ float tile[WW * 17];
  const int t = threadIdx.x;
  const int wave = t >> 6;
  const int lane = t & 63;
  const int cg = bid & 15;
  const int h = (bid >> 4) % HH;
  const int b = bid / (16 * HH);
  const int c = cg * 16 + wave;
  const float* src = feat + (size_t)((b * CC + c) * HH + h) * WW;

  float v[5];
#pragma unroll
  for (int j = 0; j < 5; ++j)
    v[j] = src[lane * 5 + j];
  // serial in-register inclusive scan of the run
#pragma unroll
  for (int j = 1; j < 5; ++j) v[j] += v[j - 1];
  // wave-wide exclusive prefix of run totals: 6 shfls
  float tot = v[4];
  float inc = tot;
#pragma unroll
  for (int d = 1; d < 64; d <<= 1) {
    float u = __shfl_up(inc, d, 64);
    if (lane >= d) inc += u;
  }
  float pre = inc - tot;               // exclusive prefix
#pragma unroll
  for (int j = 0; j < 5; ++j) v[j] += pre;
  // transpose through LDS: addr/4 = 85*lane + 17*j + wave; 85 mod 32 = 21,
  // gcd(21,32)=1 -> 2 lanes/bank (free).
#pragma unroll
  for (int j = 0; j < 5; ++j)
    tile[(lane * 5 + j) * 17 + wave] = v[j];
  __syncthreads();
  float* dst = integ + (size_t)((b * HH + h) * WW) * CC + cg * 16;
#pragma unroll
  for (int g = 0; g < 5; ++g) {
    int idx = g * 1024 + t;             // 0..5119
    int w = idx >> 4;
    int cw = idx & 15;
    dst[(size_t)w * CC + cw] = tile[w * 17 + cw];
  }
}

// ---------- K2: cumsum along H, in place on (B,H,W,C) ----------
// Two-level scan, NO serial global chain (old version: 96 dependent
// read-modify-writes at ~L3 latency each). Thread (g,l) owns channel c=cq*64+l
// and h-range [g*24, g*24+24): 24 INDEPENDENT 256B-coalesced loads (deep ILP),
// in-register inclusive scan, 4 partials exchanged via LDS, offset added,
// 24 coalesced stores. Element traffic identical (read once, write once).
// Grid 2560 x 256 = 40 waves/CU.
__global__ __launch_bounds__(256) void k2_scan(float* __restrict__ integ) {
  const int blk = blockIdx.x;            // (b, w, cq)
  const int cq = blk & 3;
  const int w = (blk >> 2) % WW;
  const int b = blk / (4 * WW);
  const int g = threadIdx.x >> 6;        // 0..3 h-group
  const int l = threadIdx.x & 63;
  float* base = integ + ((size_t)(b * HH + g * 24) * WW + w) * CC + cq * 64 + l;
  const size_t stride = (size_t)WW * CC;
  float v[24];
#pragma unroll
  for (int i = 0; i < 24; ++i) v[i] = base[(size_t)i * stride];
#pragma unroll
  for (int i = 1; i < 24; ++i) v[i] += v[i - 1];
  __shared__ float part[4][64];
  part[g][l] = v[23];
  __syncthreads();
  float off = 0.f;
#pragma unroll
  for (int gg = 0; gg < 3; ++gg)
    if (gg < g) off += part[gg][l];
#pragma unroll
  for (int i = 0; i < 24; ++i) base[(size_t)i * stride] = v[i] + off;
}

// ---------- K4: box-filtered features -> vox (bf16), K permuted to n*256+c ----------
// FOUR boxes per wave: 4 independent scale/coord/tap load streams interleave
// -> 4-deep memory ILP, 4x fewer wave drains. Lane owns 4 contiguous channels.
__global__ __launch_bounds__(256) void k4_vox(const float* __restrict__ integ,
                                              const float4* __restrict__ coords,
                                              const float* __restrict__ scales,
                                              __bf16* __restrict__ voxA) {
  const int wave = threadIdx.x >> 6;
  const int lane = threadIdx.x & 63;
  const int box0 = (blockIdx.x * 4 + wave) * 4;
#pragma unroll
  for (int u = 0; u < 4; ++u) {
    const int box = box0 + u;
    const int pix = box & (NPIX - 1);
    const int bn = box >> 14;
    const int n = bn % NLAY;
    const int b = bn / NLAY;
    const size_t row = (size_t)(b * NPIX + pix);
    bf16x4* dst = (bf16x4*)(voxA + row * KDIM + n * CC + lane * 4);
    const float scale = scales[box];
    if (scale == 0.f) {                 // wave-uniform branch
      *dst = bf16x4{(__bf16)0.f, (__bf16)0.f, (__bf16)0.f, (__bf16)0.f};
      continue;
    }
    const float4 q = coords[box];

    float xw[4]; int xi[4];
    float yw[4]; int yi[4];
    {
      float f0 = floorf(q.x); int i0 = (int)f0; float w1 = q.x - f0;
      xw[0] = (i0 >= 0 && i0 < WW) ? (1.f - w1) : 0.f;
      xw[1] = (i0 + 1 < WW) ? w1 : 0.f;
      xi[0] = min(max(i0, 0), WW - 1); xi[1] = min(max(i0 + 1, 0), WW - 1);
      float f1 = floorf(q.z); int i1 = (int)f1; float v1 = q.z - f1;
      xw[2] = (i1 >= 0 && i1 < WW) ? -(1.f - v1) : 0.f;
      xw[3] = (i1 + 1 < WW) ? -v1 : 0.f;
      xi[2] = min(max(i1, 0), WW - 1); xi[3] = min(max(i1 + 1, 0), WW - 1);
    }
    {
      float f0 = floorf(q.y); int j0 = (int)f0; float w1 = q.y - f0;
      yw[0] = (j0 >= 0 && j0 < HH) ? (1.f - w1) : 0.f;
      yw[1] = (j0 + 1 < HH) ? w1 : 0.f;
      yi[0] = min(max(j0, 0), HH - 1); yi[1] = min(max(j0 + 1, 0), HH - 1);
      float f1 = floorf(q.w); int j1 = (int)f1; float v1 = q.w - f1;
      yw[2] = (j1 >= 0 && j1 < HH) ? -(1.f - v1) : 0.f;
      yw[3] = (j1 + 1 < HH) ? -v1 : 0.f;
      yi[2] = min(max(j1, 0), HH - 1); yi[3] = min(max(j1 + 1, 0), HH - 1);
    }
    const float* base = integ + (size_t)(b * HH) * WW * CC + lane * 4;
    f32x4 val = {0.f, 0.f, 0.f, 0.f};
#pragma unroll
    for (int jj = 0; jj < 4; ++jj) {
      if (yw[jj] == 0.f) continue;          // wave-uniform branch
      const float* rp = base + (size_t)yi[jj] * WW * CC;
      f32x4 rs = {0.f, 0.f, 0.f, 0.f};
#pragma unroll
      for (int ii = 0; ii < 4; ++ii) {
        if (xw[ii] != 0.f) {
          f32x4 v = *(const f32x4*)(rp + (size_t)xi[ii] * CC);
          rs += xw[ii] * v;
        }
      }
      val += yw[jj] * rs;
    }
    val *= scale;
    *dst = bf16x4{(__bf16)val.x, (__bf16)val.y, (__bf16)val.z, (__bf16)val.w};
  }
}

// ---------- async 16B global -> LDS ----------
__device__ __forceinline__ void glds16(const void* g, void* l) {
  __builtin_amdgcn_global_load_lds(
      (const __attribute__((address_space(1))) void*)g,
      (__attribute__((address_space(3))) void*)(uint32_t)(uintptr_t)l,
      16, 0, 0);
}

// ---------- K6: GEMM  C[co, r] = sum_k Wbf[co,k] * vox[r,k]; +bias, relu ----------
// M=256 (co), N=32768, K=1280. 128x128 tiles, bf16 MFMA 16x16x32, 4-buffer LDS
// ring, depth-3 glds prefetch, fine-grained vmcnt(8) + raw s_barrier.
// Ring-4/depth-3 is the ONLY single-barrier-safe shape: stage kt+3's target
// buffer's last readers (iter kt-1) consumed their frags before barrier kt.
// Grid dim3(256,2): the two M-halves of N-tile n get linear IDs n and n+256 ==
// same XCD (mod 8) -> vox N-tile L2-shared; 512 blocks = 2 blocks/CU.
// LDS swizzle: slot (row,c) holds global chunk c ^ ((row>>1)&3) -> quarter-wave
// frag reads spread 2-way over banks (free); c ^ (row&3) was 4-way (R7: 1.97M
// SQ_LDS_BANK_CONFLICT).
__global__ __launch_bounds__(256) void k6_gemm(const __bf16* __restrict__ A,   // 256 x 1280
                                               const __bf16* __restrict__ Bm,  // 32768 x 1280
                                               const float* __restrict__ bias,
                                               float* __restrict__ out) {
  __shared__ __align__(16) __bf16 As[4][128 * 32];
  __shared__ __align__(16) __bf16 Bs[4][128 * 32];
  const int tileM = blockIdx.y * 128;
  const int tileN = blockIdx.x * 128;
  const int tid = threadIdx.x;
  const int lane = tid & 63;
  const int wave = tid >> 6;
  const int wm = (wave >> 1) * 64;
  const int wn = (wave & 1) * 64;

  f32x4 acc[4][4];
#pragma unroll
  for (int i = 0; i < 4; ++i)
#pragma unroll
    for (int j = 0; j < 4; ++j)
      acc[i][j] = f32x4{0.f, 0.f, 0.f, 0.f};

  const int r16 = lane & 15;
  const int q4 = lane >> 4;        // 0..3 -> k-chunk
  const int srow = (lane >> 2);
  const int sch = lane & 3;

  auto stage = [&](int buf, int kt) {
    const int k0 = kt * 32;
#pragma unroll
    for (int rr = 0; rr < 2; ++rr) {
      const int base_row = wave * 16 + rr * 64;
      const int row = base_row + srow;
      const int gch = sch ^ ((row >> 1) & 3);
      glds16(A  + (size_t)(tileM + row) * KDIM + k0 + gch * 8,
             (void*)(&As[buf][base_row * 32] + lane * 8));
      glds16(Bm + (size_t)(tileN + row) * KDIM + k0 + gch * 8,
             (void*)(&Bs[buf][base_row * 32] + lane * 8));
    }
  };

  stage(0, 0);
  stage(1, 1);
  stage(2, 2);
  for (int kt = 0; kt < NKT; ++kt) {
    const int cur = kt & 3;
    // wait for oldest in-flight stage only: vmcnt(N) = simm16
    // (vmcnt&0xF) | (expcnt<<4) | (lgkmcnt<<8); expcnt=7, lgkmcnt=15 = no-wait.
    if (kt < NKT - 2)       __builtin_amdgcn_s_waitcnt(0xF78);  // vmcnt(8)
    else if (kt == NKT - 2) __builtin_amdgcn_s_waitcnt(0xF74);  // vmcnt(4)
    else                    __builtin_amdgcn_s_waitcnt(0xF70);  // vmcnt(0)
    __builtin_amdgcn_s_barrier();
    if (kt + 3 < NKT) stage((kt + 3) & 3, kt + 3);   // async prefetch, depth 3
    bf16x8 af[4], bg[4];
#pragma unroll
    for (int i = 0; i < 4; ++i) {
      int m = wm + i * 16 + r16;
      af[i] = *(const bf16x8*)(&As[cur][m * 32] + (q4 ^ ((m >> 1) & 3)) * 8);
    }
#pragma unroll
    for (int j = 0; j < 4; ++j) {
      int nr = wn + j * 16 + r16;
      bg[j] = *(const bf16x8*)(&Bs[cur][nr * 32] + (q4 ^ ((nr >> 1) & 3)) * 8);
    }
#pragma unroll
    for (int i = 0; i < 4; ++i)
#pragma unroll
      for (int j = 0; j < 4; ++j)
        acc[i][j] = __builtin_amdgcn_mfma_f32_16x16x32_bf16(af[i], bg[j], acc[i][j], 0, 0, 0);
  }

#pragma unroll
  for (int i = 0; i < 4; ++i) {
#pragma unroll
    for (int j = 0; j < 4; ++j) {
      int nn = tileN + wn + j * 16 + r16;
      int bI = nn >> 14;
      int pix = nn & (NPIX - 1);
#pragma unroll
      for (int r = 0; r < 4; ++r) {
        int co = tileM + wm + i * 16 + q4 * 4 + r;
        float v = acc[i][j][r] + bias[co];
        out[(size_t)(bI * CC + co) * NPIX + pix] = fmaxf(v, 0.f);
      }
    }
  }
}

extern "C" void kernel_launch(void* const* d_in, const int* in_sizes, int n_in,
                              void* d_out, int out_size, void* d_ws, size_t ws_size,
                              hipStream_t stream) {
  const float* feat  = (const float*)d_in[0];
  const float* calib = (const float*)d_in[1];
  const float* grid  = (const float*)d_in[2];
  const float* Wc    = (const float*)d_in[3];
  const float* bc    = (const float*)d_in[4];
  float* out = (float*)d_out;

  char* ws = (char*)d_ws;
  const size_t SZ_INTEG = (size_t)BB * HH * WW * CC * 4;   // 62,914,560
  const size_t SZ_VOX   = (size_t)NDIM * KDIM * 2;         // 83,886,080
  const size_t SZ_WBF   = (size_t)CC * KDIM * 2;           //    655,360
  const size_t SZ_CRD   = (size_t)BB * NLAY * NPIX * 16;   //  2,621,440
  const size_t SZ_SCL   = (size_t)BB * NLAY * NPIX * 4;    //    655,360
  if (ws_size < SZ_INTEG + SZ_VOX + SZ_WBF + SZ_CRD + SZ_SCL) return;

  float*  integ  = (float*)ws;
  __bf16* voxA   = (__bf16*)(ws + SZ_INTEG);
  __bf16* Wbf    = (__bf16*)(ws + SZ_INTEG + SZ_VOX);
  float4* coords = (float4*)(ws + SZ_INTEG + SZ_VOX + SZ_WBF);
  float*  scales = (float*)(ws + SZ_INTEG + SZ_VOX + SZ_WBF + SZ_CRD);

  k1f<<<dim3(BB * HH * 16 + 480), dim3(1024), 0, stream>>>(
      feat, integ, grid, calib, Wc, coords, scales, Wbf);
  k2_scan<<<dim3(BB * WW * 4), dim3(256), 0, stream>>>(integ);
  k4_vox<<<dim3(BB * NLAY * NPIX / 16), dim3(256), 0, stream>>>(integ, coords, scales, voxA);
  k6_gemm<<<dim3(NDIM / 128, 2), dim3(256), 0, stream>>>(Wbf, voxA, bc, out);
}

// Round 3
// 191.607 us; speedup vs baseline: 1.0255x; 1.0255x over previous
//
#include <hip/hip_runtime.h>
#include <hip/hip_bf16.h>
#include <stdint.h>

#define BB 2
#define CC 256
#define HH 96
#define WW 320
#define NPIX 16384
#define NLAY 5
#define KDIM 1280   // CC*NLAY
#define NDIM 32768  // BB*NPIX
#define NKT (KDIM / 32)   // 40 K-tiles

typedef float f32x4 __attribute__((ext_vector_type(4)));
typedef float f32x2 __attribute__((ext_vector_type(2)));
typedef __bf16 bf16x8 __attribute__((ext_vector_type(8)));
typedef __bf16 bf16x4 __attribute__((ext_vector_type(4)));

// ---------- K1 (+K3+K5 fused as extra blocks): ----------
// blocks [0,1536): cumsum along W + transpose (B,C,H,W) -> (B,H,W,C).
//   R1 (interleaved shfl, chain 30->7) : null. R2 (run-scan, DS 40->16,
//   VALUBusy 26->17%): null. => not chain-, DS- or VALU-bound. k1f moves
//   100MB at 2.3TB/s while fillBuffer hits 6.4TB/s same-run => access
//   pattern. R3: 32-channel blocks (full 128B-line ownership per block,
//   grid 3072->1536) + float4 stores (8x128B fully-covered contiguous
//   segments per store instr, 3 rounds vs 5 scalar) + 2 channel streams
//   per wave (2x ILP).
// blocks [1536,2016): box geometry + Wc repack (1920 old 256-thread blocks
// repacked 4-per-1024-block). Branch is block-uniform -> k1's __syncthreads
// is only reached by k1 blocks (safe).
__global__ __launch_bounds__(1024) void k1f(const float* __restrict__ feat,
                                            float* __restrict__ integ,
                                            const float* __restrict__ gridp,
                                            const float* __restrict__ calib,
                                            const float* __restrict__ Wc,
                                            float4* __restrict__ coords,
                                            float* __restrict__ scales,
                                            __bf16* __restrict__ Wbf) {
  const int bid = blockIdx.x;
  if (bid >= BB * HH * 8) {
    // ---- K3/K5 part ----
    const int vbid = (bid - BB * HH * 8) * 4 + (threadIdx.x >> 8);
    const int vt = threadIdx.x & 255;
    if (vbid >= 640) {                  // K5: repack Wc (co, c*5+n) -> bf16 (co, n*256+c)
      int o = (vbid - 640) * 256 + vt;
      int co = o / KDIM;
      int kk = o % KDIM;
      int n = kk >> 8;
      int c = kk & 255;
      Wbf[o] = (__bf16)Wc[co * KDIM + c * NLAY + n];
      return;
    }
    // K3: one thread per box. Keep SEPARATE from k4 — fusing into k4 makes all
    // 64 lanes redundantly compute 16 fp32 divides (R3: k4 57->173us).
    int box = vbid * 256 + vt;          // ((b*5+n)<<14) | pix
    int pix = box & (NPIX - 1);
    int bn = box >> 14;
    int n = bn % NLAY;
    int b = bn / NLAY;
    const float* cb = calib + b * 12;
    float c00 = cb[0], c01 = cb[1], c02 = cb[2], c03 = cb[3];
    float c10 = cb[4], c11 = cb[5], c12 = cb[6], c13 = cb[7];
    float c20 = cb[8], c21 = cb[9], c22 = cb[10], c23 = cb[11];
    float gx = gridp[pix * 3 + 0], gy = gridp[pix * 3 + 1], gz = gridp[pix * 3 + 2];
    float zoff = 32.0f * (float)n;
    const float ox[8] = {-12.5f, 12.5f, 12.5f, -12.5f, -12.5f, 12.5f, 12.5f, -12.5f};
    const float oy[8] = {-12.5f, -12.5f, 12.5f, 12.5f, -12.5f, -12.5f, 12.5f, 12.5f};
    float xmn = 1e30f, ymn = 1e30f, xmx = -1e30f, ymx = -1e30f;
#pragma unroll
    for (int k = 0; k < 8; ++k) {
      float X = gx + ox[k];
      float Y = gy + oy[k];
      float Z = gz + zoff + ((k >= 4) ? 32.0f : 0.0f);
      float px = c00 * X + c01 * Y + c02 * Z + c03;
      float py = c10 * X + c11 * Y + c12 * Z + c13;
      float pz = c20 * X + c21 * Y + c22 * Z + c23;
      float d = fmaxf(pz, 1e-6f);
      float nx = fminf(fmaxf(2.0f * (px / d) / 320.0f - 1.0f, -1.0f), 0.95f);
      float ny = fminf(fmaxf(2.0f * (py / d) / 96.0f - 1.0f, -1.0f), 0.95f);
      xmn = fminf(xmn, nx); xmx = fmaxf(xmx, nx);
      ymn = fminf(ymn, ny); ymx = fmaxf(ymx, ny);
    }
    float dx = xmx - xmn, dy = ymx - ymn;
    float area = (dx * dy) * 30720.0f + 1e-6f;
    bool vis = (area > 1e-6f) && (area < 9216.0f);
    float X0 = ((xmn + 1.0f) * 320.0f - 1.0f) * 0.5f;
    float Y0 = ((ymn + 1.0f) * 96.0f - 1.0f) * 0.5f;
    float X1 = ((xmx + 1.0f) * 320.0f - 1.0f) * 0.5f;
    float Y1 = ((ymx + 1.0f) * 96.0f - 1.0f) * 0.5f;
    coords[box] = make_float4(X0, Y0, X1, Y1);
    scales[box] = vis ? 1.0f / area : 0.0f;
    return;
  }
  // ---- K1 part: 32 channels per block, wave scans 2 channel rows ----
  __shared__ float tile[WW * 33];       // [w][c'] pitch 33; run-5 write stride
                                        // 165%32=5 (2-way, free); store-side
                                        // read bank (w+4cq+r)%32 (2-way, free)
  const int t = threadIdx.x;
  const int wave = t >> 6;
  const int lane = t & 63;
  const int cg = bid & 7;
  const int h = (bid >> 3) % HH;
  const int b = bid / (8 * HH);
  const int c0 = cg * 32 + wave * 2;
  const float* s0 = feat + (size_t)((b * CC + c0) * HH + h) * WW;
  const float* s1 = s0 + (size_t)HH * WW;

  float va[5], vb[5];
#pragma unroll
  for (int j = 0; j < 5; ++j) va[j] = s0[lane * 5 + j];
#pragma unroll
  for (int j = 0; j < 5; ++j) vb[j] = s1[lane * 5 + j];
  // serial in-register inclusive scan of each run
#pragma unroll
  for (int j = 1; j < 5; ++j) { va[j] += va[j - 1]; vb[j] += vb[j - 1]; }
  // wave-wide exclusive prefix of run totals: 6 shfl steps, 2 streams
  float ta = va[4], tb = vb[4];
  float ia = ta, ib = tb;
#pragma unroll
  for (int d = 1; d < 64; d <<= 1) {
    float ua = __shfl_up(ia, d, 64);
    float ub = __shfl_up(ib, d, 64);
    if (lane >= d) { ia += ua; ib += ub; }
  }
  float pa = ia - ta, pb = ib - tb;     // exclusive prefixes
#pragma unroll
  for (int j = 0; j < 5; ++j) { va[j] += pa; vb[j] += pb; }
#pragma unroll
  for (int j = 0; j < 5; ++j) {
    int w = lane * 5 + j;
    tile[w * 33 + wave * 2]     = va[j];
    tile[w * 33 + wave * 2 + 1] = vb[j];
  }
  __syncthreads();
  // store: float4 per thread; per instruction a wave covers 8 w-rows x
  // 128B contiguous (full lines, single-owner block).
  float* dst = integ + (size_t)((b * HH + h) * WW) * CC + cg * 32;
#pragma unroll
  for (int r = 0; r < 3; ++r) {
    int idx = r * 1024 + t;             // 0..2559
    if (idx < 2560) {
      int w = idx >> 3;
      int cq = (idx & 7) * 4;
      float4 o = make_float4(tile[w * 33 + cq + 0], tile[w * 33 + cq + 1],
                             tile[w * 33 + cq + 2], tile[w * 33 + cq + 3]);
      *(float4*)(dst + (size_t)w * CC + cq) = o;
    }
  }
}

// ---------- K2: cumsum along H, in place on (B,H,W,C) ----------
// Two-level scan, NO serial global chain (old version: 96 dependent
// read-modify-writes at ~L3 latency each). Thread (g,l) owns channel c=cq*64+l
// and h-range [g*24, g*24+24): 24 INDEPENDENT 256B-coalesced loads (deep ILP),
// in-register inclusive scan, 4 partials exchanged via LDS, offset added,
// 24 coalesced stores. Element traffic identical (read once, write once).
// Grid 2560 x 256 = 40 waves/CU.
__global__ __launch_bounds__(256) void k2_scan(float* __restrict__ integ) {
  const int blk = blockIdx.x;            // (b, w, cq)
  const int cq = blk & 3;
  const int w = (blk >> 2) % WW;
  const int b = blk / (4 * WW);
  const int g = threadIdx.x >> 6;        // 0..3 h-group
  const int l = threadIdx.x & 63;
  float* base = integ + ((size_t)(b * HH + g * 24) * WW + w) * CC + cq * 64 + l;
  const size_t stride = (size_t)WW * CC;
  float v[24];
#pragma unroll
  for (int i = 0; i < 24; ++i) v[i] = base[(size_t)i * stride];
#pragma unroll
  for (int i = 1; i < 24; ++i) v[i] += v[i - 1];
  __shared__ float part[4][64];
  part[g][l] = v[23];
  __syncthreads();
  float off = 0.f;
#pragma unroll
  for (int gg = 0; gg < 3; ++gg)
    if (gg < g) off += part[gg][l];
#pragma unroll
  for (int i = 0; i < 24; ++i) base[(size_t)i * stride] = v[i] + off;
}

// ---------- K4: box-filtered features -> vox (bf16), K permuted to n*256+c ----------
// FOUR boxes per wave: 4 independent scale/coord/tap load streams interleave
// -> 4-deep memory ILP, 4x fewer wave drains. Lane owns 4 contiguous channels.
__global__ __launch_bounds__(256) void k4_vox(const float* __restrict__ integ,
                                              const float4* __restrict__ coords,
                                              const float* __restrict__ scales,
                                              __bf16* __restrict__ voxA) {
  const int wave = threadIdx.x >> 6;
  const int lane = threadIdx.x & 63;
  const int box0 = (blockIdx.x * 4 + wave) * 4;
#pragma unroll
  for (int u = 0; u < 4; ++u) {
    const int box = box0 + u;
    const int pix = box & (NPIX - 1);
    const int bn = box >> 14;
    const int n = bn % NLAY;
    const int b = bn / NLAY;
    const size_t row = (size_t)(b * NPIX + pix);
    bf16x4* dst = (bf16x4*)(voxA + row * KDIM + n * CC + lane * 4);
    const float scale = scales[box];
    if (scale == 0.f) {                 // wave-uniform branch
      *dst = bf16x4{(__bf16)0.f, (__bf16)0.f, (__bf16)0.f, (__bf16)0.f};
      continue;
    }
    const float4 q = coords[box];

    float xw[4]; int xi[4];
    float yw[4]; int yi[4];
    {
      float f0 = floorf(q.x); int i0 = (int)f0; float w1 = q.x - f0;
      xw[0] = (i0 >= 0 && i0 < WW) ? (1.f - w1) : 0.f;
      xw[1] = (i0 + 1 < WW) ? w1 : 0.f;
      xi[0] = min(max(i0, 0), WW - 1); xi[1] = min(max(i0 + 1, 0), WW - 1);
      float f1 = floorf(q.z); int i1 = (int)f1; float v1 = q.z - f1;
      xw[2] = (i1 >= 0 && i1 < WW) ? -(1.f - v1) : 0.f;
      xw[3] = (i1 + 1 < WW) ? -v1 : 0.f;
      xi[2] = min(max(i1, 0), WW - 1); xi[3] = min(max(i1 + 1, 0), WW - 1);
    }
    {
      float f0 = floorf(q.y); int j0 = (int)f0; float w1 = q.y - f0;
      yw[0] = (j0 >= 0 && j0 < HH) ? (1.f - w1) : 0.f;
      yw[1] = (j0 + 1 < HH) ? w1 : 0.f;
      yi[0] = min(max(j0, 0), HH - 1); yi[1] = min(max(j0 + 1, 0), HH - 1);
      float f1 = floorf(q.w); int j1 = (int)f1; float v1 = q.w - f1;
      yw[2] = (j1 >= 0 && j1 < HH) ? -(1.f - v1) : 0.f;
      yw[3] = (j1 + 1 < HH) ? -v1 : 0.f;
      yi[2] = min(max(j1, 0), HH - 1); yi[3] = min(max(j1 + 1, 0), HH - 1);
    }
    const float* base = integ + (size_t)(b * HH) * WW * CC + lane * 4;
    f32x4 val = {0.f, 0.f, 0.f, 0.f};
#pragma unroll
    for (int jj = 0; jj < 4; ++jj) {
      if (yw[jj] == 0.f) continue;          // wave-uniform branch
      const float* rp = base + (size_t)yi[jj] * WW * CC;
      f32x4 rs = {0.f, 0.f, 0.f, 0.f};
#pragma unroll
      for (int ii = 0; ii < 4; ++ii) {
        if (xw[ii] != 0.f) {
          f32x4 v = *(const f32x4*)(rp + (size_t)xi[ii] * CC);
          rs += xw[ii] * v;
        }
      }
      val += yw[jj] * rs;
    }
    val *= scale;
    *dst = bf16x4{(__bf16)val.x, (__bf16)val.y, (__bf16)val.z, (__bf16)val.w};
  }
}

// ---------- async 16B global -> LDS ----------
__device__ __forceinline__ void glds16(const void* g, void* l) {
  __builtin_amdgcn_global_load_lds(
      (const __attribute__((address_space(1))) void*)g,
      (__attribute__((address_space(3))) void*)(uint32_t)(uintptr_t)l,
      16, 0, 0);
}

// ---------- K6: GEMM  C[co, r] = sum_k Wbf[co,k] * vox[r,k]; +bias, relu ----------
// M=256 (co), N=32768, K=1280. 128x128 tiles, bf16 MFMA 16x16x32, 4-buffer LDS
// ring, depth-3 glds prefetch, fine-grained vmcnt(8) + raw s_barrier.
// Ring-4/depth-3 is the ONLY single-barrier-safe shape: stage kt+3's target
// buffer's last readers (iter kt-1) consumed their frags before barrier kt.
// Grid dim3(256,2): the two M-halves of N-tile n get linear IDs n and n+256 ==
// same XCD (mod 8) -> vox N-tile L2-shared; 512 blocks = 2 blocks/CU.
// LDS swizzle: slot (row,c) holds global chunk c ^ ((row>>1)&3) -> quarter-wave
// frag reads spread 2-way over banks (free); c ^ (row&3) was 4-way (R7: 1.97M
// SQ_LDS_BANK_CONFLICT).
__global__ __launch_bounds__(256) void k6_gemm(const __bf16* __restrict__ A,   // 256 x 1280
                                               const __bf16* __restrict__ Bm,  // 32768 x 1280
                                               const float* __restrict__ bias,
                                               float* __restrict__ out) {
  __shared__ __align__(16) __bf16 As[4][128 * 32];
  __shared__ __align__(16) __bf16 Bs[4][128 * 32];
  const int tileM = blockIdx.y * 128;
  const int tileN = blockIdx.x * 128;
  const int tid = threadIdx.x;
  const int lane = tid & 63;
  const int wave = tid >> 6;
  const int wm = (wave >> 1) * 64;
  const int wn = (wave & 1) * 64;

  f32x4 acc[4][4];
#pragma unroll
  for (int i = 0; i < 4; ++i)
#pragma unroll
    for (int j = 0; j < 4; ++j)
      acc[i][j] = f32x4{0.f, 0.f, 0.f, 0.f};

  const int r16 = lane & 15;
  const int q4 = lane >> 4;        // 0..3 -> k-chunk
  const int srow = (lane >> 2);
  const int sch = lane & 3;

  auto stage = [&](int buf, int kt) {
    const int k0 = kt * 32;
#pragma unroll
    for (int rr = 0; rr < 2; ++rr) {
      const int base_row = wave * 16 + rr * 64;
      const int row = base_row + srow;
      const int gch = sch ^ ((row >> 1) & 3);
      glds16(A  + (size_t)(tileM + row) * KDIM + k0 + gch * 8,
             (void*)(&As[buf][base_row * 32] + lane * 8));
      glds16(Bm + (size_t)(tileN + row) * KDIM + k0 + gch * 8,
             (void*)(&Bs[buf][base_row * 32] + lane * 8));
    }
  };

  stage(0, 0);
  stage(1, 1);
  stage(2, 2);
  for (int kt = 0; kt < NKT; ++kt) {
    const int cur = kt & 3;
    // wait for oldest in-flight stage only: vmcnt(N) = simm16
    // (vmcnt&0xF) | (expcnt<<4) | (lgkmcnt<<8); expcnt=7, lgkmcnt=15 = no-wait.
    if (kt < NKT - 2)       __builtin_amdgcn_s_waitcnt(0xF78);  // vmcnt(8)
    else if (kt == NKT - 2) __builtin_amdgcn_s_waitcnt(0xF74);  // vmcnt(4)
    else                    __builtin_amdgcn_s_waitcnt(0xF70);  // vmcnt(0)
    __builtin_amdgcn_s_barrier();
    if (kt + 3 < NKT) stage((kt + 3) & 3, kt + 3);   // async prefetch, depth 3
    bf16x8 af[4], bg[4];
#pragma unroll
    for (int i = 0; i < 4; ++i) {
      int m = wm + i * 16 + r16;
      af[i] = *(const bf16x8*)(&As[cur][m * 32] + (q4 ^ ((m >> 1) & 3)) * 8);
    }
#pragma unroll
    for (int j = 0; j < 4; ++j) {
      int nr = wn + j * 16 + r16;
      bg[j] = *(const bf16x8*)(&Bs[cur][nr * 32] + (q4 ^ ((nr >> 1) & 3)) * 8);
    }
#pragma unroll
    for (int i = 0; i < 4; ++i)
#pragma unroll
      for (int j = 0; j < 4; ++j)
        acc[i][j] = __builtin_amdgcn_mfma_f32_16x16x32_bf16(af[i], bg[j], acc[i][j], 0, 0, 0);
  }

#pragma unroll
  for (int i = 0; i < 4; ++i) {
#pragma unroll
    for (int j = 0; j < 4; ++j) {
      int nn = tileN + wn + j * 16 + r16;
      int bI = nn >> 14;
      int pix = nn & (NPIX - 1);
#pragma unroll
      for (int r = 0; r < 4; ++r) {
        int co = tileM + wm + i * 16 + q4 * 4 + r;
        float v = acc[i][j][r] + bias[co];
        out[(size_t)(bI * CC + co) * NPIX + pix] = fmaxf(v, 0.f);
      }
    }
  }
}

extern "C" void kernel_launch(void* const* d_in, const int* in_sizes, int n_in,
                              void* d_out, int out_size, void* d_ws, size_t ws_size,
                              hipStream_t stream) {
  const float* feat  = (const float*)d_in[0];
  const float* calib = (const float*)d_in[1];
  const float* grid  = (const float*)d_in[2];
  const float* Wc    = (const float*)d_in[3];
  const float* bc    = (const float*)d_in[4];
  float* out = (float*)d_out;

  char* ws = (char*)d_ws;
  const size_t SZ_INTEG = (size_t)BB * HH * WW * CC * 4;   // 62,914,560
  const size_t SZ_VOX   = (size_t)NDIM * KDIM * 2;         // 83,886,080
  const size_t SZ_WBF   = (size_t)CC * KDIM * 2;           //    655,360
  const size_t SZ_CRD   = (size_t)BB * NLAY * NPIX * 16;   //  2,621,440
  const size_t SZ_SCL   = (size_t)BB * NLAY * NPIX * 4;    //    655,360
  if (ws_size < SZ_INTEG + SZ_VOX + SZ_WBF + SZ_CRD + SZ_SCL) return;

  float*  integ  = (float*)ws;
  __bf16* voxA   = (__bf16*)(ws + SZ_INTEG);
  __bf16* Wbf    = (__bf16*)(ws + SZ_INTEG + SZ_VOX);
  float4* coords = (float4*)(ws + SZ_INTEG + SZ_VOX + SZ_WBF);
  float*  scales = (float*)(ws + SZ_INTEG + SZ_VOX + SZ_WBF + SZ_CRD);

  k1f<<<dim3(BB * HH * 8 + 480), dim3(1024), 0, stream>>>(
      feat, integ, grid, calib, Wc, coords, scales, Wbf);
  k2_scan<<<dim3(BB * WW * 4), dim3(256), 0, stream>>>(integ);
  k4_vox<<<dim3(BB * NLAY * NPIX / 16), dim3(256), 0, stream>>>(integ, coords, scales, voxA);
  k6_gemm<<<dim3(NDIM / 128, 2), dim3(256), 0, stream>>>(Wbf, voxA, bc, out);
}

// Round 4
// 189.409 us; speedup vs baseline: 1.0374x; 1.0116x over previous
//
#include <hip/hip_runtime.h>
#include <hip/hip_bf16.h>
#include <stdint.h>

#define BB 2
#define CC 256
#define HH 96
#define WW 320
#define NPIX 16384
#define NLAY 5
#define KDIM 1280   // CC*NLAY
#define NDIM 32768  // BB*NPIX
#define NKT (KDIM / 32)   // 40 K-tiles

typedef float f32x4 __attribute__((ext_vector_type(4)));
typedef float f32x2 __attribute__((ext_vector_type(2)));
typedef __bf16 bf16x8 __attribute__((ext_vector_type(8)));
typedef __bf16 bf16x4 __attribute__((ext_vector_type(4)));

// ---------- K1 (+K3+K5 fused as extra blocks): ----------
// blocks [0,480): box geometry + Wc repack — FIRST so they overlap with k1
//   instead of tail-serializing (they used to be blockIdx >= 1536 -> pure
//   ~5us tail after all k1 blocks drained).
// blocks [480, 480+1536): cumsum along W + transpose (B,C,H,W)->(B,H,W,C),
//   32 channels per block (full 128B-line ownership, R3) with float4 stores.
//   R4: read side made memcpy-class — stage feat via coalesced float4 +
//   ds_write_b128 into LDS, lane ds_reads its 5-float run (stride 5 words,
//   gcd(5,32)=1 -> 2 lanes/bank, free). R1 (shfl chain), R2 (DS count) were
//   null; R2 proved DS has headroom, so +15 DS ops/wave here is safe.
__global__ __launch_bounds__(1024) void k1f(const float* __restrict__ feat,
                                            float* __restrict__ integ,
                                            const float* __restrict__ gridp,
                                            const float* __restrict__ calib,
                                            const float* __restrict__ Wc,
                                            float4* __restrict__ coords,
                                            float* __restrict__ scales,
                                            __bf16* __restrict__ Wbf) {
  const int bid = blockIdx.x;
  if (bid < 480) {
    // ---- K3/K5 part ----
    const int vbid = bid * 4 + (threadIdx.x >> 8);
    const int vt = threadIdx.x & 255;
    if (vbid >= 640) {                  // K5: repack Wc (co, c*5+n) -> bf16 (co, n*256+c)
      int o = (vbid - 640) * 256 + vt;
      int co = o / KDIM;
      int kk = o % KDIM;
      int n = kk >> 8;
      int c = kk & 255;
      Wbf[o] = (__bf16)Wc[co * KDIM + c * NLAY + n];
      return;
    }
    // K3: one thread per box. Keep SEPARATE from k4 — fusing into k4 makes all
    // 64 lanes redundantly compute 16 fp32 divides (R3: k4 57->173us).
    int box = vbid * 256 + vt;          // ((b*5+n)<<14) | pix
    int pix = box & (NPIX - 1);
    int bn = box >> 14;
    int n = bn % NLAY;
    int b = bn / NLAY;
    const float* cb = calib + b * 12;
    float c00 = cb[0], c01 = cb[1], c02 = cb[2], c03 = cb[3];
    float c10 = cb[4], c11 = cb[5], c12 = cb[6], c13 = cb[7];
    float c20 = cb[8], c21 = cb[9], c22 = cb[10], c23 = cb[11];
    float gx = gridp[pix * 3 + 0], gy = gridp[pix * 3 + 1], gz = gridp[pix * 3 + 2];
    float zoff = 32.0f * (float)n;
    const float ox[8] = {-12.5f, 12.5f, 12.5f, -12.5f, -12.5f, 12.5f, 12.5f, -12.5f};
    const float oy[8] = {-12.5f, -12.5f, 12.5f, 12.5f, -12.5f, -12.5f, 12.5f, 12.5f};
    float xmn = 1e30f, ymn = 1e30f, xmx = -1e30f, ymx = -1e30f;
#pragma unroll
    for (int k = 0; k < 8; ++k) {
      float X = gx + ox[k];
      float Y = gy + oy[k];
      float Z = gz + zoff + ((k >= 4) ? 32.0f : 0.0f);
      float px = c00 * X + c01 * Y + c02 * Z + c03;
      float py = c10 * X + c11 * Y + c12 * Z + c13;
      float pz = c20 * X + c21 * Y + c22 * Z + c23;
      float d = fmaxf(pz, 1e-6f);
      float nx = fminf(fmaxf(2.0f * (px / d) / 320.0f - 1.0f, -1.0f), 0.95f);
      float ny = fminf(fmaxf(2.0f * (py / d) / 96.0f - 1.0f, -1.0f), 0.95f);
      xmn = fminf(xmn, nx); xmx = fmaxf(xmx, nx);
      ymn = fminf(ymn, ny); ymx = fmaxf(ymx, ny);
    }
    float dx = xmx - xmn, dy = ymx - ymn;
    float area = (dx * dy) * 30720.0f + 1e-6f;
    bool vis = (area > 1e-6f) && (area < 9216.0f);
    float X0 = ((xmn + 1.0f) * 320.0f - 1.0f) * 0.5f;
    float Y0 = ((ymn + 1.0f) * 96.0f - 1.0f) * 0.5f;
    float X1 = ((xmx + 1.0f) * 320.0f - 1.0f) * 0.5f;
    float Y1 = ((ymx + 1.0f) * 96.0f - 1.0f) * 0.5f;
    coords[box] = make_float4(X0, Y0, X1, Y1);
    scales[box] = vis ? 1.0f / area : 0.0f;
    return;
  }
  // ---- K1 part: 32 channels per block, wave scans 2 channel rows ----
  // tile serves two roles (aliased, sync-separated):
  //   phase L/R: raw feat rows, layout [cr][w]   (32 x 320, pitch 320)
  //   phase T/S: scanned transposed [w][c']      (320 x 32, pitch 33)
  __shared__ float tile[WW * 33];       // 42.2 KB; 1024 thr -> 2 blocks/CU
  const int t = threadIdx.x;
  const int wave = t >> 6;
  const int lane = t & 63;
  const int kb = bid - 480;
  const int cg = kb & 7;
  const int h = (kb >> 3) % HH;
  const int b = kb / (8 * HH);
  const int c0 = cg * 32;

  // phase L: coalesced float4 global reads -> ds_write_b128, layout [cr][w]
  {
    const float* fb = feat + (size_t)((b * CC + c0) * HH + h) * WW;
    const size_t crstride = (size_t)HH * WW;
#pragma unroll
    for (int r = 0; r < 3; ++r) {
      int idx = r * 1024 + t;           // 0..2559 float4 slots
      if (idx < 2560) {
        int cr = idx / 80;              // channel row 0..31
        int wq = idx - cr * 80;         // float4 slot 0..79
        f32x4 v = *(const f32x4*)(fb + cr * crstride + wq * 4);
        *(f32x4*)(&tile[cr * WW + wq * 4]) = v;
      }
    }
  }
  __syncthreads();
  // phase R: lane reads its two 5-float runs (channels ca=2*wave, cb=+1)
  const int ca = wave * 2, cbn = wave * 2 + 1;
  float va[5], vb[5];
#pragma unroll
  for (int j = 0; j < 5; ++j) va[j] = tile[ca * WW + lane * 5 + j];
#pragma unroll
  for (int j = 0; j < 5; ++j) vb[j] = tile[cbn * WW + lane * 5 + j];
  // serial in-register inclusive scan of each run
#pragma unroll
  for (int j = 1; j < 5; ++j) { va[j] += va[j - 1]; vb[j] += vb[j - 1]; }
  // wave-wide exclusive prefix of run totals: 6 shfl steps, 2 streams
  float ta = va[4], tb = vb[4];
  float ia = ta, ib = tb;
#pragma unroll
  for (int d = 1; d < 64; d <<= 1) {
    float ua = __shfl_up(ia, d, 64);
    float ub = __shfl_up(ib, d, 64);
    if (lane >= d) { ia += ua; ib += ub; }
  }
  float pa = ia - ta, pb = ib - tb;     // exclusive prefixes
#pragma unroll
  for (int j = 0; j < 5; ++j) { va[j] += pa; vb[j] += pb; }
  __syncthreads();                      // all runs read before tile is reused
  // phase T: write scanned values transposed [w][c'], pitch 33
#pragma unroll
  for (int j = 0; j < 5; ++j) {
    int w = lane * 5 + j;
    tile[w * 33 + ca]  = va[j];
    tile[w * 33 + cbn] = vb[j];
  }
  __syncthreads();
  // phase S: float4 stores; per wave-instr 8 w-rows x 128B full-line segments
  float* dst = integ + (size_t)((b * HH + h) * WW) * CC + cg * 32;
#pragma unroll
  for (int r = 0; r < 3; ++r) {
    int idx = r * 1024 + t;             // 0..2559
    if (idx < 2560) {
      int w = idx >> 3;
      int cq = (idx & 7) * 4;
      float4 o = make_float4(tile[w * 33 + cq + 0], tile[w * 33 + cq + 1],
                             tile[w * 33 + cq + 2], tile[w * 33 + cq + 3]);
      *(float4*)(dst + (size_t)w * CC + cq) = o;
    }
  }
}

// ---------- K2: cumsum along H, in place on (B,H,W,C) ----------
// Two-level scan, no serial global chain. R4: f32x2 per lane (2 channels) —
// halves instruction count, 512B contiguous segments per wave-instr at the
// 320KB h-stride. Thread (g,l) owns channels cq*128+2l(+1), h-range
// [g*24, g*24+24). Grid 1280 x 256 = 20 waves/CU.
__global__ __launch_bounds__(256) void k2_scan(float* __restrict__ integ) {
  const int blk = blockIdx.x;            // (b, w, cq)
  const int cq = blk & 1;
  const int w = (blk >> 1) % WW;
  const int b = blk / (2 * WW);
  const int g = threadIdx.x >> 6;        // 0..3 h-group
  const int l = threadIdx.x & 63;
  float* base = integ + ((size_t)(b * HH + g * 24) * WW + w) * CC + cq * 128 + l * 2;
  const size_t stride = (size_t)WW * CC;
  f32x2 v[24];
#pragma unroll
  for (int i = 0; i < 24; ++i) v[i] = *(const f32x2*)(base + (size_t)i * stride);
#pragma unroll
  for (int i = 1; i < 24; ++i) v[i] += v[i - 1];
  __shared__ f32x2 part[4][64];
  part[g][l] = v[23];
  __syncthreads();
  f32x2 off = {0.f, 0.f};
#pragma unroll
  for (int gg = 0; gg < 3; ++gg)
    if (gg < g) off += part[gg][l];
#pragma unroll
  for (int i = 0; i < 24; ++i) *(f32x2*)(base + (size_t)i * stride) = v[i] + off;
}

// ---------- K4: box-filtered features -> vox (bf16), K permuted to n*256+c ----------
// FOUR boxes per wave: 4 independent scale/coord/tap load streams interleave
// -> 4-deep memory ILP, 4x fewer wave drains. Lane owns 4 contiguous channels.
__global__ __launch_bounds__(256) void k4_vox(const float* __restrict__ integ,
                                              const float4* __restrict__ coords,
                                              const float* __restrict__ scales,
                                              __bf16* __restrict__ voxA) {
  const int wave = threadIdx.x >> 6;
  const int lane = threadIdx.x & 63;
  const int box0 = (blockIdx.x * 4 + wave) * 4;
#pragma unroll
  for (int u = 0; u < 4; ++u) {
    const int box = box0 + u;
    const int pix = box & (NPIX - 1);
    const int bn = box >> 14;
    const int n = bn % NLAY;
    const int b = bn / NLAY;
    const size_t row = (size_t)(b * NPIX + pix);
    bf16x4* dst = (bf16x4*)(voxA + row * KDIM + n * CC + lane * 4);
    const float scale = scales[box];
    if (scale == 0.f) {                 // wave-uniform branch
      *dst = bf16x4{(__bf16)0.f, (__bf16)0.f, (__bf16)0.f, (__bf16)0.f};
      continue;
    }
    const float4 q = coords[box];

    float xw[4]; int xi[4];
    float yw[4]; int yi[4];
    {
      float f0 = floorf(q.x); int i0 = (int)f0; float w1 = q.x - f0;
      xw[0] = (i0 >= 0 && i0 < WW) ? (1.f - w1) : 0.f;
      xw[1] = (i0 + 1 < WW) ? w1 : 0.f;
      xi[0] = min(max(i0, 0), WW - 1); xi[1] = min(max(i0 + 1, 0), WW - 1);
      float f1 = floorf(q.z); int i1 = (int)f1; float v1 = q.z - f1;
      xw[2] = (i1 >= 0 && i1 < WW) ? -(1.f - v1) : 0.f;
      xw[3] = (i1 + 1 < WW) ? -v1 : 0.f;
      xi[2] = min(max(i1, 0), WW - 1); xi[3] = min(max(i1 + 1, 0), WW - 1);
    }
    {
      float f0 = floorf(q.y); int j0 = (int)f0; float w1 = q.y - f0;
      yw[0] = (j0 >= 0 && j0 < HH) ? (1.f - w1) : 0.f;
      yw[1] = (j0 + 1 < HH) ? w1 : 0.f;
      yi[0] = min(max(j0, 0), HH - 1); yi[1] = min(max(j0 + 1, 0), HH - 1);
      float f1 = floorf(q.w); int j1 = (int)f1; float v1 = q.w - f1;
      yw[2] = (j1 >= 0 && j1 < HH) ? -(1.f - v1) : 0.f;
      yw[3] = (j1 + 1 < HH) ? -v1 : 0.f;
      yi[2] = min(max(j1, 0), HH - 1); yi[3] = min(max(j1 + 1, 0), HH - 1);
    }
    const float* base = integ + (size_t)(b * HH) * WW * CC + lane * 4;
    f32x4 val = {0.f, 0.f, 0.f, 0.f};
#pragma unroll
    for (int jj = 0; jj < 4; ++jj) {
      if (yw[jj] == 0.f) continue;          // wave-uniform branch
      const float* rp = base + (size_t)yi[jj] * WW * CC;
      f32x4 rs = {0.f, 0.f, 0.f, 0.f};
#pragma unroll
      for (int ii = 0; ii < 4; ++ii) {
        if (xw[ii] != 0.f) {
          f32x4 v = *(const f32x4*)(rp + (size_t)xi[ii] * CC);
          rs += xw[ii] * v;
        }
      }
      val += yw[jj] * rs;
    }
    val *= scale;
    *dst = bf16x4{(__bf16)val.x, (__bf16)val.y, (__bf16)val.z, (__bf16)val.w};
  }
}

// ---------- async 16B global -> LDS ----------
__device__ __forceinline__ void glds16(const void* g, void* l) {
  __builtin_amdgcn_global_load_lds(
      (const __attribute__((address_space(1))) void*)g,
      (__attribute__((address_space(3))) void*)(uint32_t)(uintptr_t)l,
      16, 0, 0);
}

// ---------- K6: GEMM  C[co, r] = sum_k Wbf[co,k] * vox[r,k]; +bias, relu ----------
// M=256 (co), N=32768, K=1280. 128x128 tiles, bf16 MFMA 16x16x32, 4-buffer LDS
// ring, depth-3 glds prefetch, fine-grained vmcnt(8) + raw s_barrier.
// Ring-4/depth-3 is the ONLY single-barrier-safe shape: stage kt+3's target
// buffer's last readers (iter kt-1) consumed their frags before barrier kt.
// Grid dim3(256,2): the two M-halves of N-tile n get linear IDs n and n+256 ==
// same XCD (mod 8) -> vox N-tile L2-shared; 512 blocks = 2 blocks/CU.
// LDS swizzle: slot (row,c) holds global chunk c ^ ((row>>1)&3) -> quarter-wave
// frag reads spread 2-way over banks (free); c ^ (row&3) was 4-way (R7: 1.97M
// SQ_LDS_BANK_CONFLICT).
__global__ __launch_bounds__(256) void k6_gemm(const __bf16* __restrict__ A,   // 256 x 1280
                                               const __bf16* __restrict__ Bm,  // 32768 x 1280
                                               const float* __restrict__ bias,
                                               float* __restrict__ out) {
  __shared__ __align__(16) __bf16 As[4][128 * 32];
  __shared__ __align__(16) __bf16 Bs[4][128 * 32];
  const int tileM = blockIdx.y * 128;
  const int tileN = blockIdx.x * 128;
  const int tid = threadIdx.x;
  const int lane = tid & 63;
  const int wave = tid >> 6;
  const int wm = (wave >> 1) * 64;
  const int wn = (wave & 1) * 64;

  f32x4 acc[4][4];
#pragma unroll
  for (int i = 0; i < 4; ++i)
#pragma unroll
    for (int j = 0; j < 4; ++j)
      acc[i][j] = f32x4{0.f, 0.f, 0.f, 0.f};

  const int r16 = lane & 15;
  const int q4 = lane >> 4;        // 0..3 -> k-chunk
  const int srow = (lane >> 2);
  const int sch = lane & 3;

  auto stage = [&](int buf, int kt) {
    const int k0 = kt * 32;
#pragma unroll
    for (int rr = 0; rr < 2; ++rr) {
      const int base_row = wave * 16 + rr * 64;
      const int row = base_row + srow;
      const int gch = sch ^ ((row >> 1) & 3);
      glds16(A  + (size_t)(tileM + row) * KDIM + k0 + gch * 8,
             (void*)(&As[buf][base_row * 32] + lane * 8));
      glds16(Bm + (size_t)(tileN + row) * KDIM + k0 + gch * 8,
             (void*)(&Bs[buf][base_row * 32] + lane * 8));
    }
  };

  stage(0, 0);
  stage(1, 1);
  stage(2, 2);
  for (int kt = 0; kt < NKT; ++kt) {
    const int cur = kt & 3;
    // wait for oldest in-flight stage only: vmcnt(N) = simm16
    // (vmcnt&0xF) | (expcnt<<4) | (lgkmcnt<<8); expcnt=7, lgkmcnt=15 = no-wait.
    if (kt < NKT - 2)       __builtin_amdgcn_s_waitcnt(0xF78);  // vmcnt(8)
    else if (kt == NKT - 2) __builtin_amdgcn_s_waitcnt(0xF74);  // vmcnt(4)
    else                    __builtin_amdgcn_s_waitcnt(0xF70);  // vmcnt(0)
    __builtin_amdgcn_s_barrier();
    if (kt + 3 < NKT) stage((kt + 3) & 3, kt + 3);   // async prefetch, depth 3
    bf16x8 af[4], bg[4];
#pragma unroll
    for (int i = 0; i < 4; ++i) {
      int m = wm + i * 16 + r16;
      af[i] = *(const bf16x8*)(&As[cur][m * 32] + (q4 ^ ((m >> 1) & 3)) * 8);
    }
#pragma unroll
    for (int j = 0; j < 4; ++j) {
      int nr = wn + j * 16 + r16;
      bg[j] = *(const bf16x8*)(&Bs[cur][nr * 32] + (q4 ^ ((nr >> 1) & 3)) * 8);
    }
#pragma unroll
    for (int i = 0; i < 4; ++i)
#pragma unroll
      for (int j = 0; j < 4; ++j)
        acc[i][j] = __builtin_amdgcn_mfma_f32_16x16x32_bf16(af[i], bg[j], acc[i][j], 0, 0, 0);
  }

#pragma unroll
  for (int i = 0; i < 4; ++i) {
#pragma unroll
    for (int j = 0; j < 4; ++j) {
      int nn = tileN + wn + j * 16 + r16;
      int bI = nn >> 14;
      int pix = nn & (NPIX - 1);
#pragma unroll
      for (int r = 0; r < 4; ++r) {
        int co = tileM + wm + i * 16 + q4 * 4 + r;
        float v = acc[i][j][r] + bias[co];
        out[(size_t)(bI * CC + co) * NPIX + pix] = fmaxf(v, 0.f);
      }
    }
  }
}

extern "C" void kernel_launch(void* const* d_in, const int* in_sizes, int n_in,
                              void* d_out, int out_size, void* d_ws, size_t ws_size,
                              hipStream_t stream) {
  const float* feat  = (const float*)d_in[0];
  const float* calib = (const float*)d_in[1];
  const float* grid  = (const float*)d_in[2];
  const float* Wc    = (const float*)d_in[3];
  const float* bc    = (const float*)d_in[4];
  float* out = (float*)d_out;

  char* ws = (char*)d_ws;
  const size_t SZ_INTEG = (size_t)BB * HH * WW * CC * 4;   // 62,914,560
  const size_t SZ_VOX   = (size_t)NDIM * KDIM * 2;         // 83,886,080
  const size_t SZ_WBF   = (size_t)CC * KDIM * 2;           //    655,360
  const size_t SZ_CRD   = (size_t)BB * NLAY * NPIX * 16;   //  2,621,440
  const size_t SZ_SCL   = (size_t)BB * NLAY * NPIX * 4;    //    655,360
  if (ws_size < SZ_INTEG + SZ_VOX + SZ_WBF + SZ_CRD + SZ_SCL) return;

  float*  integ  = (float*)ws;
  __bf16* voxA   = (__bf16*)(ws + SZ_INTEG);
  __bf16* Wbf    = (__bf16*)(ws + SZ_INTEG + SZ_VOX);
  float4* coords = (float4*)(ws + SZ_INTEG + SZ_VOX + SZ_WBF);
  float*  scales = (float*)(ws + SZ_INTEG + SZ_VOX + SZ_WBF + SZ_CRD);

  k1f<<<dim3(BB * HH * 8 + 480), dim3(1024), 0, stream>>>(
      feat, integ, grid, calib, Wc, coords, scales, Wbf);
  k2_scan<<<dim3(BB * WW * 2), dim3(256), 0, stream>>>(integ);
  k4_vox<<<dim3(BB * NLAY * NPIX / 16), dim3(256), 0, stream>>>(integ, coords, scales, voxA);
  k6_gemm<<<dim3(NDIM / 128, 2), dim3(256), 0, stream>>>(Wbf, voxA, bc, out);
}

// Round 5
// 160.316 us; speedup vs baseline: 1.2257x; 1.1815x over previous
//
#include <hip/hip_runtime.h>
#include <hip/hip_bf16.h>
#include <stdint.h>

#define BB 2
#define CC 256
#define HH 96
#define WW 320
#define NPIX 16384
#define NLAY 5
#define KDIM 1280   // CC*NLAY
#define NDIM 32768  // BB*NPIX
#define NKT (KDIM / 32)   // 40 K-tiles
#define NGRP 256    // NDIM/128 output row groups (k6 N-tiles)

typedef float f32x4 __attribute__((ext_vector_type(4)));
typedef float f32x2 __attribute__((ext_vector_type(2)));
typedef __bf16 bf16x8 __attribute__((ext_vector_type(8)));
typedef __bf16 bf16x4 __attribute__((ext_vector_type(4)));

// ---------- K1 (+K3+K5 fused as extra blocks): ----------
// blocks [0,480): box geometry + Wc repack (overlaps with k1, R4).
//   R5: K3 additionally emits mask8[g*5+n] = OR(vis) over the 128-pix group g
//   — one byte per (group,layer), written by exactly ONE block (2 groups per
//   vbid) via wave ballots: no atomics, no init of poisoned workspace.
// blocks [480, 480+1536): cumsum along W + transpose (B,C,H,W)->(B,H,W,C),
//   32-ch blocks / full 128B-line ownership (R3), LDS-staged reads (R4).
__global__ __launch_bounds__(1024) void k1f(const float* __restrict__ feat,
                                            float* __restrict__ integ,
                                            const float* __restrict__ gridp,
                                            const float* __restrict__ calib,
                                            const float* __restrict__ Wc,
                                            float4* __restrict__ coords,
                                            float* __restrict__ scales,
                                            __bf16* __restrict__ Wbf,
                                            uint8_t* __restrict__ mask8) {
  const int bid = blockIdx.x;
  if (bid < 480) {
    // ---- K3/K5 part ----
    const int vbid = bid * 4 + (threadIdx.x >> 8);
    const int vt = threadIdx.x & 255;
    if (vbid >= 640) {                  // K5: repack Wc (co, c*5+n) -> bf16 (co, n*256+c)
      int o = (vbid - 640) * 256 + vt;
      int co = o / KDIM;
      int kk = o % KDIM;
      int n = kk >> 8;
      int c = kk & 255;
      Wbf[o] = (__bf16)Wc[co * KDIM + c * NLAY + n];
      return;
    }
    // K3: one thread per box. (K3 vs K5 split is block-uniform: 640 = 160*4.)
    int box = vbid * 256 + vt;          // ((b*5+n)<<14) | pix
    int pix = box & (NPIX - 1);
    int bn = box >> 14;
    int n = bn % NLAY;
    int b = bn / NLAY;
    const float* cb = calib + b * 12;
    float c00 = cb[0], c01 = cb[1], c02 = cb[2], c03 = cb[3];
    float c10 = cb[4], c11 = cb[5], c12 = cb[6], c13 = cb[7];
    float c20 = cb[8], c21 = cb[9], c22 = cb[10], c23 = cb[11];
    float gx = gridp[pix * 3 + 0], gy = gridp[pix * 3 + 1], gz = gridp[pix * 3 + 2];
    float zoff = 32.0f * (float)n;
    const float ox[8] = {-12.5f, 12.5f, 12.5f, -12.5f, -12.5f, 12.5f, 12.5f, -12.5f};
    const float oy[8] = {-12.5f, -12.5f, 12.5f, 12.5f, -12.5f, -12.5f, 12.5f, 12.5f};
    float xmn = 1e30f, ymn = 1e30f, xmx = -1e30f, ymx = -1e30f;
#pragma unroll
    for (int k = 0; k < 8; ++k) {
      float X = gx + ox[k];
      float Y = gy + oy[k];
      float Z = gz + zoff + ((k >= 4) ? 32.0f : 0.0f);
      float px = c00 * X + c01 * Y + c02 * Z + c03;
      float py = c10 * X + c11 * Y + c12 * Z + c13;
      float pz = c20 * X + c21 * Y + c22 * Z + c23;
      float d = fmaxf(pz, 1e-6f);
      float nx = fminf(fmaxf(2.0f * (px / d) / 320.0f - 1.0f, -1.0f), 0.95f);
      float ny = fminf(fmaxf(2.0f * (py / d) / 96.0f - 1.0f, -1.0f), 0.95f);
      xmn = fminf(xmn, nx); xmx = fmaxf(xmx, nx);
      ymn = fminf(ymn, ny); ymx = fmaxf(ymx, ny);
    }
    float dx = xmx - xmn, dy = ymx - ymn;
    float area = (dx * dy) * 30720.0f + 1e-6f;
    bool vis = (area > 1e-6f) && (area < 9216.0f);
    // group-visibility mask: wave w covers pix [pixbase+64w, +64); groups of
    // 128 pix = waves {0,1} -> g0, {2,3} -> g0+1. One byte per (g,n), single
    // writer -> no atomics, no init needed on poisoned ws.
    {
      __shared__ uint32_t kf[16];
      unsigned long long bal = __ballot(vis);
      if ((threadIdx.x & 63) == 0) kf[threadIdx.x >> 6] = (bal != 0ull) ? 1u : 0u;
      __syncthreads();
      if (vt == 0) {
        int vb = threadIdx.x >> 8;      // vbid-local 0..3
        int vbid2 = bid * 4 + vb;
        int bn2 = vbid2 >> 6;
        int n2 = bn2 % NLAY, b2 = bn2 / NLAY;
        int g0 = b2 * 128 + (vbid2 & 63) * 2;
        mask8[g0 * 5 + n2]       = (uint8_t)(kf[vb * 4 + 0] | kf[vb * 4 + 1]);
        mask8[(g0 + 1) * 5 + n2] = (uint8_t)(kf[vb * 4 + 2] | kf[vb * 4 + 3]);
      }
    }
    float X0 = ((xmn + 1.0f) * 320.0f - 1.0f) * 0.5f;
    float Y0 = ((ymn + 1.0f) * 96.0f - 1.0f) * 0.5f;
    float X1 = ((xmx + 1.0f) * 320.0f - 1.0f) * 0.5f;
    float Y1 = ((ymx + 1.0f) * 96.0f - 1.0f) * 0.5f;
    coords[box] = make_float4(X0, Y0, X1, Y1);
    scales[box] = vis ? 1.0f / area : 0.0f;
    return;
  }
  // ---- K1 part: 32 channels per block, wave scans 2 channel rows ----
  __shared__ float tile[WW * 33];       // 42.2 KB; 1024 thr -> 2 blocks/CU
  const int t = threadIdx.x;
  const int wave = t >> 6;
  const int lane = t & 63;
  const int kb = bid - 480;
  const int cg = kb & 7;
  const int h = (kb >> 3) % HH;
  const int b = kb / (8 * HH);
  const int c0 = cg * 32;

  // phase L: coalesced float4 global reads -> ds_write_b128, layout [cr][w]
  {
    const float* fb = feat + (size_t)((b * CC + c0) * HH + h) * WW;
    const size_t crstride = (size_t)HH * WW;
#pragma unroll
    for (int r = 0; r < 3; ++r) {
      int idx = r * 1024 + t;           // 0..2559 float4 slots
      if (idx < 2560) {
        int cr = idx / 80;              // channel row 0..31
        int wq = idx - cr * 80;         // float4 slot 0..79
        f32x4 v = *(const f32x4*)(fb + cr * crstride + wq * 4);
        *(f32x4*)(&tile[cr * WW + wq * 4]) = v;
      }
    }
  }
  __syncthreads();
  // phase R: lane reads its two 5-float runs (channels ca=2*wave, cb=+1)
  const int ca = wave * 2, cbn = wave * 2 + 1;
  float va[5], vb[5];
#pragma unroll
  for (int j = 0; j < 5; ++j) va[j] = tile[ca * WW + lane * 5 + j];
#pragma unroll
  for (int j = 0; j < 5; ++j) vb[j] = tile[cbn * WW + lane * 5 + j];
#pragma unroll
  for (int j = 1; j < 5; ++j) { va[j] += va[j - 1]; vb[j] += vb[j - 1]; }
  float ta = va[4], tb = vb[4];
  float ia = ta, ib = tb;
#pragma unroll
  for (int d = 1; d < 64; d <<= 1) {
    float ua = __shfl_up(ia, d, 64);
    float ub = __shfl_up(ib, d, 64);
    if (lane >= d) { ia += ua; ib += ub; }
  }
  float pa = ia - ta, pb = ib - tb;     // exclusive prefixes
#pragma unroll
  for (int j = 0; j < 5; ++j) { va[j] += pa; vb[j] += pb; }
  __syncthreads();                      // all runs read before tile is reused
  // phase T: write scanned values transposed [w][c'], pitch 33
#pragma unroll
  for (int j = 0; j < 5; ++j) {
    int w = lane * 5 + j;
    tile[w * 33 + ca]  = va[j];
    tile[w * 33 + cbn] = vb[j];
  }
  __syncthreads();
  // phase S: float4 stores; per wave-instr 8 w-rows x 128B full-line segments
  float* dst = integ + (size_t)((b * HH + h) * WW) * CC + cg * 32;
#pragma unroll
  for (int r = 0; r < 3; ++r) {
    int idx = r * 1024 + t;             // 0..2559
    if (idx < 2560) {
      int w = idx >> 3;
      int cq = (idx & 7) * 4;
      float4 o = make_float4(tile[w * 33 + cq + 0], tile[w * 33 + cq + 1],
                             tile[w * 33 + cq + 2], tile[w * 33 + cq + 3]);
      *(float4*)(dst + (size_t)w * CC + cq) = o;
    }
  }
}

// ---------- K2: cumsum along H, in place on (B,H,W,C) ----------
// Two-level scan. R5: f32x4 per lane (4 channels) — 1KB contiguous segments
// per wave-instr, 24-deep independent-load ILP. Grid 640 x 256.
__global__ __launch_bounds__(256) void k2_scan(float* __restrict__ integ) {
  const int blk = blockIdx.x;            // (b, w)
  const int w = blk % WW;
  const int b = blk / WW;
  const int g = threadIdx.x >> 6;        // 0..3 h-group
  const int l = threadIdx.x & 63;
  float* base = integ + ((size_t)(b * HH + g * 24) * WW + w) * CC + l * 4;
  const size_t stride = (size_t)WW * CC;
  f32x4 v[24];
#pragma unroll
  for (int i = 0; i < 24; ++i) v[i] = *(const f32x4*)(base + (size_t)i * stride);
#pragma unroll
  for (int i = 1; i < 24; ++i) v[i] += v[i - 1];
  __shared__ f32x4 part[4][64];
  part[g][l] = v[23];
  __syncthreads();
  f32x4 off = {0.f, 0.f, 0.f, 0.f};
#pragma unroll
  for (int gg = 0; gg < 3; ++gg)
    if (gg < g) off += part[gg][l];
#pragma unroll
  for (int i = 0; i < 24; ++i) *(f32x4*)(base + (size_t)i * stride) = v[i] + off;
}

// ---------- K4: box-filtered features -> vox (bf16), K permuted to n*256+c ----------
// FOUR boxes per wave, 4-deep memory ILP. R5: wave early-out when the whole
// (128-pix group, layer) is invisible (mask byte 0) — skips tap loads AND the
// zero-writes; those vox rows stay poisoned but k6 provably never reads them
// (same mask gates its K-tiles).
__global__ __launch_bounds__(256) void k4_vox(const float* __restrict__ integ,
                                              const float4* __restrict__ coords,
                                              const float* __restrict__ scales,
                                              __bf16* __restrict__ voxA,
                                              const uint8_t* __restrict__ mask8) {
  const int wave = threadIdx.x >> 6;
  const int lane = threadIdx.x & 63;
  const int box0 = (blockIdx.x * 4 + wave) * 4;
  {
    const int pix0 = box0 & (NPIX - 1);
    const int bn0 = box0 >> 14;
    const int n0 = bn0 % NLAY, b0 = bn0 / NLAY;
    if (mask8[((b0 * NPIX + pix0) >> 7) * 5 + n0] == 0) return;  // wave-uniform
  }
#pragma unroll
  for (int u = 0; u < 4; ++u) {
    const int box = box0 + u;
    const int pix = box & (NPIX - 1);
    const int bn = box >> 14;
    const int n = bn % NLAY;
    const int b = bn / NLAY;
    const size_t row = (size_t)(b * NPIX + pix);
    bf16x4* dst = (bf16x4*)(voxA + row * KDIM + n * CC + lane * 4);
    const float scale = scales[box];
    if (scale == 0.f) {                 // wave-uniform branch
      *dst = bf16x4{(__bf16)0.f, (__bf16)0.f, (__bf16)0.f, (__bf16)0.f};
      continue;
    }
    const float4 q = coords[box];

    float xw[4]; int xi[4];
    float yw[4]; int yi[4];
    {
      float f0 = floorf(q.x); int i0 = (int)f0; float w1 = q.x - f0;
      xw[0] = (i0 >= 0 && i0 < WW) ? (1.f - w1) : 0.f;
      xw[1] = (i0 + 1 < WW) ? w1 : 0.f;
      xi[0] = min(max(i0, 0), WW - 1); xi[1] = min(max(i0 + 1, 0), WW - 1);
      float f1 = floorf(q.z); int i1 = (int)f1; float v1 = q.z - f1;
      xw[2] = (i1 >= 0 && i1 < WW) ? -(1.f - v1) : 0.f;
      xw[3] = (i1 + 1 < WW) ? -v1 : 0.f;
      xi[2] = min(max(i1, 0), WW - 1); xi[3] = min(max(i1 + 1, 0), WW - 1);
    }
    {
      float f0 = floorf(q.y); int j0 = (int)f0; float w1 = q.y - f0;
      yw[0] = (j0 >= 0 && j0 < HH) ? (1.f - w1) : 0.f;
      yw[1] = (j0 + 1 < HH) ? w1 : 0.f;
      yi[0] = min(max(j0, 0), HH - 1); yi[1] = min(max(j0 + 1, 0), HH - 1);
      float f1 = floorf(q.w); int j1 = (int)f1; float v1 = q.w - f1;
      yw[2] = (j1 >= 0 && j1 < HH) ? -(1.f - v1) : 0.f;
      yw[3] = (j1 + 1 < HH) ? -v1 : 0.f;
      yi[2] = min(max(j1, 0), HH - 1); yi[3] = min(max(j1 + 1, 0), HH - 1);
    }
    const float* base = integ + (size_t)(b * HH) * WW * CC + lane * 4;
    f32x4 val = {0.f, 0.f, 0.f, 0.f};
#pragma unroll
    for (int jj = 0; jj < 4; ++jj) {
      if (yw[jj] == 0.f) continue;          // wave-uniform branch
      const float* rp = base + (size_t)yi[jj] * WW * CC;
      f32x4 rs = {0.f, 0.f, 0.f, 0.f};
#pragma unroll
      for (int ii = 0; ii < 4; ++ii) {
        if (xw[ii] != 0.f) {
          f32x4 v = *(const f32x4*)(rp + (size_t)xi[ii] * CC);
          rs += xw[ii] * v;
        }
      }
      val += yw[jj] * rs;
    }
    val *= scale;
    *dst = bf16x4{(__bf16)val.x, (__bf16)val.y, (__bf16)val.z, (__bf16)val.w};
  }
}

// ---------- async 16B global -> LDS ----------
__device__ __forceinline__ void glds16(const void* g, void* l) {
  __builtin_amdgcn_global_load_lds(
      (const __attribute__((address_space(1))) void*)g,
      (__attribute__((address_space(3))) void*)(uint32_t)(uintptr_t)l,
      16, 0, 0);
}

// ---------- K6: GEMM  C[co, r] = sum_k Wbf[co,k] * vox[r,k]; +bias, relu ----------
// M=256, N=32768, K=1280. 128x128 tiles, bf16 MFMA 16x16x32, 4-buffer LDS
// ring, depth-3 glds prefetch, in-flight-aware vmcnt + raw s_barrier.
// R5: K-loop runs over the COMPRESSED list of active K-tiles (8 per visible
// layer, from mask8) — skipped tiles are provably all-zero vox (identical
// math), so FETCH and MFMA work scale with the visible fraction.
__global__ __launch_bounds__(256) void k6_gemm(const __bf16* __restrict__ A,   // 256 x 1280
                                               const __bf16* __restrict__ Bm,  // 32768 x 1280
                                               const float* __restrict__ bias,
                                               float* __restrict__ out,
                                               const uint8_t* __restrict__ mask8) {
  __shared__ __align__(16) __bf16 As[4][128 * 32];
  __shared__ __align__(16) __bf16 Bs[4][128 * 32];
  __shared__ uint8_t ktsS[NKT];
  __shared__ int LsS;
  const int tileM = blockIdx.y * 128;
  const int tileN = blockIdx.x * 128;
  const int tid = threadIdx.x;
  const int lane = tid & 63;
  const int wave = tid >> 6;
  const int wm = (wave >> 1) * 64;
  const int wn = (wave & 1) * 64;

  if (tid == 0) {
    const uint8_t* mg = mask8 + blockIdx.x * 5;   // N-tile group == blockIdx.x
    int L = 0;
#pragma unroll
    for (int n = 0; n < NLAY; ++n)
      if (mg[n]) {
#pragma unroll
        for (int kk = 0; kk < 8; ++kk) ktsS[L++] = (uint8_t)(n * 8 + kk);
      }
    LsS = L;
  }

  f32x4 acc[4][4];
#pragma unroll
  for (int i = 0; i < 4; ++i)
#pragma unroll
    for (int j = 0; j < 4; ++j)
      acc[i][j] = f32x4{0.f, 0.f, 0.f, 0.f};

  const int r16 = lane & 15;
  const int q4 = lane >> 4;        // 0..3 -> k-chunk
  const int srow = (lane >> 2);
  const int sch = lane & 3;

  auto stage = [&](int buf, int kt) {
    const int k0 = kt * 32;
#pragma unroll
    for (int rr = 0; rr < 2; ++rr) {
      const int base_row = wave * 16 + rr * 64;
      const int row = base_row + srow;
      const int gch = sch ^ ((row >> 1) & 3);
      glds16(A  + (size_t)(tileM + row) * KDIM + k0 + gch * 8,
             (void*)(&As[buf][base_row * 32] + lane * 8));
      glds16(Bm + (size_t)(tileN + row) * KDIM + k0 + gch * 8,
             (void*)(&Bs[buf][base_row * 32] + lane * 8));
    }
  };

  __syncthreads();                       // ktsS/LsS visible
  const int L = LsS;
#pragma unroll
  for (int s = 0; s < 3; ++s)
    if (s < L) stage(s, ktsS[s]);
  for (int i = 0; i < L; ++i) {
    const int cur = i & 3;
    const int rem = L - i;               // stages in flight = min(rem, 3)
    if (rem >= 3)      __builtin_amdgcn_s_waitcnt(0xF78);  // vmcnt(8)
    else if (rem == 2) __builtin_amdgcn_s_waitcnt(0xF74);  // vmcnt(4)
    else               __builtin_amdgcn_s_waitcnt(0xF70);  // vmcnt(0)
    __builtin_amdgcn_s_barrier();
    if (i + 3 < L) stage((i + 3) & 3, ktsS[i + 3]);   // async prefetch, depth 3
    bf16x8 af[4], bg[4];
#pragma unroll
    for (int ii = 0; ii < 4; ++ii) {
      int m = wm + ii * 16 + r16;
      af[ii] = *(const bf16x8*)(&As[cur][m * 32] + (q4 ^ ((m >> 1) & 3)) * 8);
    }
#pragma unroll
    for (int j = 0; j < 4; ++j) {
      int nr = wn + j * 16 + r16;
      bg[j] = *(const bf16x8*)(&Bs[cur][nr * 32] + (q4 ^ ((nr >> 1) & 3)) * 8);
    }
#pragma unroll
    for (int ii = 0; ii < 4; ++ii)
#pragma unroll
      for (int j = 0; j < 4; ++j)
        acc[ii][j] = __builtin_amdgcn_mfma_f32_16x16x32_bf16(af[ii], bg[j], acc[ii][j], 0, 0, 0);
  }

#pragma unroll
  for (int i = 0; i < 4; ++i) {
#pragma unroll
    for (int j = 0; j < 4; ++j) {
      int nn = tileN + wn + j * 16 + r16;
      int bI = nn >> 14;
      int pix = nn & (NPIX - 1);
#pragma unroll
      for (int r = 0; r < 4; ++r) {
        int co = tileM + wm + i * 16 + q4 * 4 + r;
        float v = acc[i][j][r] + bias[co];
        out[(size_t)(bI * CC + co) * NPIX + pix] = fmaxf(v, 0.f);
      }
    }
  }
}

extern "C" void kernel_launch(void* const* d_in, const int* in_sizes, int n_in,
                              void* d_out, int out_size, void* d_ws, size_t ws_size,
                              hipStream_t stream) {
  const float* feat  = (const float*)d_in[0];
  const float* calib = (const float*)d_in[1];
  const float* grid  = (const float*)d_in[2];
  const float* Wc    = (const float*)d_in[3];
  const float* bc    = (const float*)d_in[4];
  float* out = (float*)d_out;

  char* ws = (char*)d_ws;
  const size_t SZ_INTEG = (size_t)BB * HH * WW * CC * 4;   // 62,914,560
  const size_t SZ_VOX   = (size_t)NDIM * KDIM * 2;         // 83,886,080
  const size_t SZ_WBF   = (size_t)CC * KDIM * 2;           //    655,360
  const size_t SZ_CRD   = (size_t)BB * NLAY * NPIX * 16;   //  2,621,440
  const size_t SZ_SCL   = (size_t)BB * NLAY * NPIX * 4;    //    655,360
  const size_t SZ_MSK   = (size_t)NGRP * NLAY;             //      1,280
  if (ws_size < SZ_INTEG + SZ_VOX + SZ_WBF + SZ_CRD + SZ_SCL + SZ_MSK) return;

  float*   integ  = (float*)ws;
  __bf16*  voxA   = (__bf16*)(ws + SZ_INTEG);
  __bf16*  Wbf    = (__bf16*)(ws + SZ_INTEG + SZ_VOX);
  float4*  coords = (float4*)(ws + SZ_INTEG + SZ_VOX + SZ_WBF);
  float*   scales = (float*)(ws + SZ_INTEG + SZ_VOX + SZ_WBF + SZ_CRD);
  uint8_t* mask8  = (uint8_t*)(ws + SZ_INTEG + SZ_VOX + SZ_WBF + SZ_CRD + SZ_SCL);

  k1f<<<dim3(BB * HH * 8 + 480), dim3(1024), 0, stream>>>(
      feat, integ, grid, calib, Wc, coords, scales, Wbf, mask8);
  k2_scan<<<dim3(BB * WW), dim3(256), 0, stream>>>(integ);
  k4_vox<<<dim3(BB * NLAY * NPIX / 16), dim3(256), 0, stream>>>(integ, coords, scales, voxA, mask8);
  k6_gemm<<<dim3(NDIM / 128, 2), dim3(256), 0, stream>>>(Wbf, voxA, bc, out, mask8);
}